// Round 6
// baseline (1030.763 us; speedup 1.0000x reference)
//
#include <hip/hip_runtime.h>

// Problem constants
constexpr int Bz = 512;   // batch
constexpr int Tz = 256;   // seq len
constexpr int Hz = 256;   // hidden
constexpr int Pz = 14;    // predict dim
constexpr int GB = 32;    // batch groups
constexpr int GS = 8;     // hidden slices per group
constexpr int BT = 16;    // batch per group (512/32)
constexpr int KP = 264;   // LDS h row stride (shorts)
constexpr int XS = 260;   // x LDS row stride (floats)
constexpr int HWORDS = 65536;  // u64 words per h buffer: 32 slw * 512 B * 4 q

typedef short s8v __attribute__((ext_vector_type(8)));
typedef float f4v __attribute__((ext_vector_type(4)));
typedef unsigned long long u64;

__device__ __forceinline__ short f2bf(float f) {
  unsigned u = __float_as_uint(f);
  u = (u + 0x7fffu + ((u >> 16) & 1u)) >> 16;   // RNE
  return (short)u;
}
__device__ __forceinline__ float bf2f(short s) {
  return __uint_as_float(((unsigned)(unsigned short)s) << 16);
}
__device__ __forceinline__ float sigm(float v) { return 1.0f / (1.0f + __expf(-v)); }
__device__ __forceinline__ float tanh_f(float v) { return 1.0f - 2.0f / (__expf(2.0f * v) + 1.0f); }

__device__ __forceinline__ u64 llc_load(const u64* p) {
  return __hip_atomic_load(p, __ATOMIC_RELAXED, __HIP_MEMORY_SCOPE_AGENT);
}
__device__ __forceinline__ void llc_store(u64* p, u64 v) {
  __hip_atomic_store(p, v, __ATOMIC_RELAXED, __HIP_MEMORY_SCOPE_AGENT);
}

// Pre-stamp the boundary buffers: h0 buf1 & h1 buf0 = stamp 1, h1 buf1 = stamp 2
// (data part zero = initial hidden state). Stamp at step s is s+2; consumer at
// step s expects s+1 on both arrays.
__global__ void hinit(u64* __restrict__ h0g, u64* __restrict__ h1g) {
  int i = blockIdx.x * 256 + threadIdx.x;   // 65536 threads, one word per region
  h0g[HWORDS + i] = (u64)1 << 32;
  h1g[i]          = (u64)1 << 32;
  h1g[HWORDS + i] = (u64)2 << 32;
}

// R6: stamped-mailbox exchange. h word = (stamp<<32)|two-bf16. Store IS the
// flag: no group counter, no fetch_add, no tid0 poll, no store-drain barrier.
// Loop order: poll -> LDS write -> sync -> MFMA+epilogue -> sync -> stores,
// so store-acks drain under the NEXT poll (off critical path). Buffer-reuse
// safety is transitive: overwrite at s+2 requires staging s+1 data from all
// peers, which they store only after completing their step-s polls.
__global__ void __launch_bounds__(256, 1)
lstm2(const float* __restrict__ x,
      const float* __restrict__ w_ih0, const float* __restrict__ w_hh0,
      const float* __restrict__ b_ih0, const float* __restrict__ b_hh0,
      const float* __restrict__ w_ih1, const float* __restrict__ w_hh1,
      const float* __restrict__ b_ih1, const float* __restrict__ b_hh1,
      const float* __restrict__ w_lin, const float* __restrict__ b_lin,
      float* __restrict__ out,
      u64* __restrict__ h0g, u64* __restrict__ h1g)
{
  const int blk  = blockIdx.x;
  const int g    = blk >> 3;      // batch group (32)
  const int sl   = blk & 7;       // hidden slice (8)
  const int tid  = threadIdx.x;
  const int w    = tid >> 6;      // wave
  const int lane = tid & 63;
  const int q    = lane >> 4;
  const int l15  = lane & 15;     // batch within group
  const int gbase = g * BT;

  extern __shared__ char smem_raw[];
  short* h0s = (short*)smem_raw;          // [BT][KP] staged h0[s-1], kpos order
  short* h1s = h0s + BT * KP;             // [BT][KP] staged h1[s-2]
  float* xls = (float*)(h1s + BT * KP);   // [BT][XS] x preload
  float* wls = xls + BT * XS;             // [Pz][256] w_lin permuted to kpos order

  // ---- one-time: weights -> register A-fragments (permuted k gather) ----
  // kpos = sl*32 + w*8 + q*2 + j  <->  k_true = sl*32 + w*4 + q + 16*j
  s8v Wf[3][2][8];   // [mat: hh0, ih1, hh1][mti][kt]
  {
    const float* wsrc[3] = {w_hh0, w_ih1, w_hh1};
    #pragma unroll
    for (int mat = 0; mat < 3; ++mat) {
      #pragma unroll
      for (int mti = 0; mti < 2; ++mti) {
        int rr = (w + mti * 4) * 16 + l15;          // rr = unit*4+gate
        int grow = (rr & 3) * Hz + sl * 32 + (rr >> 2);
        const float* p = wsrc[mat] + (size_t)grow * Hz;
        #pragma unroll
        for (int kt = 0; kt < 8; ++kt) {
          s8v f;
          #pragma unroll
          for (int j = 0; j < 8; ++j) {
            int ktrue = kt * 32 + q * 4 + (j >> 1) + 16 * (j & 1);
            f[j] = f2bf(p[ktrue]);
          }
          Wf[mat][mti][kt] = f;
        }
      }
    }
  }
  // per-lane epilogue constants: units uA = w*4+q, uB = 16+uA; gates r=0..3
  const int uA = w * 4 + q, uB = 16 + w * 4 + q;
  float wihA[4], wihB[4], b0A[4], b0B[4], b1A[4], b1B[4];
  #pragma unroll
  for (int r = 0; r < 4; ++r) {
    int ga_ = r * Hz + sl * 32 + uA;
    int gb_ = r * Hz + sl * 32 + uB;
    wihA[r] = w_ih0[ga_];              wihB[r] = w_ih0[gb_];
    b0A[r]  = b_ih0[ga_] + b_hh0[ga_]; b0B[r]  = b_ih0[gb_] + b_hh0[gb_];
    b1A[r]  = b_ih1[ga_] + b_hh1[ga_]; b1B[r]  = b_ih1[gb_] + b_hh1[gb_];
  }
  float c0A = 0.f, c0B = 0.f, c1A = 0.f, c1B = 0.f;

  // ---- preload x and permuted w_lin ----
  for (int i = tid; i < BT * (Tz / 4); i += 256) {
    int b = i >> 6, c4 = i & 63;
    f4v v = *(const f4v*)(x + (size_t)(gbase + b) * Tz + c4 * 4);
    *(f4v*)(xls + b * XS + c4 * 4) = v;
  }
  if (sl == 0) {
    for (int i = tid; i < Pz * Hz; i += 256) {
      int p = i >> 8, kpos = i & 255;
      int sl2 = kpos >> 5, w2 = (kpos >> 3) & 3, q2 = (kpos >> 1) & 3, jj = kpos & 1;
      wls[i] = w_lin[p * Hz + sl2 * 32 + w2 * 4 + q2 + 16 * jj];
    }
  }

  // consumer slot mapping: slot k -> i = k*256+tid; slw = i>>6; w64 = i&63
  // global idx = slw*2048 + (gbase)*4 + w64; LDS: b = w64>>2, q2 = w64&3,
  // u32 data -> shorts at b*KP + slw*8 + q2*2
  for (int s = 0; s <= Tz; ++s) {
    // ---- A: stamped poll of h0[s-1] (buf (s+1)&1) and h1[s-2] (buf s&1) ----
    u64 v0[8], v1[8];
    {
      const u64* p0 = h0g + (size_t)((s + 1) & 1) * HWORDS;
      const u64* p1 = h1g + (size_t)(s & 1) * HWORDS;
      const unsigned expd = (unsigned)(s + 1);
      #pragma unroll
      for (int k = 0; k < 8; ++k) {
        int i = k * 256 + tid;
        size_t gi = (size_t)(i >> 6) * 2048 + (size_t)gbase * 4 + (i & 63);
        v0[k] = llc_load(p0 + gi);
        v1[k] = llc_load(p1 + gi);
      }
      while (true) {
        bool ok = true;
        #pragma unroll
        for (int k = 0; k < 8; ++k)
          ok = ok && ((unsigned)(v0[k] >> 32) == expd)
                  && ((unsigned)(v1[k] >> 32) == expd);
        if (ok) break;
        __builtin_amdgcn_s_sleep(1);
        #pragma unroll
        for (int k = 0; k < 8; ++k) {
          int i = k * 256 + tid;
          size_t gi = (size_t)(i >> 6) * 2048 + (size_t)gbase * 4 + (i & 63);
          if ((unsigned)(v0[k] >> 32) != expd) v0[k] = llc_load(p0 + gi);
          if ((unsigned)(v1[k] >> 32) != expd) v1[k] = llc_load(p1 + gi);
        }
      }
    }
    // ---- B: strip stamps -> LDS ----
    #pragma unroll
    for (int k = 0; k < 8; ++k) {
      int i = k * 256 + tid;
      int slw = i >> 6, w64 = i & 63;
      int b = w64 >> 2, q2 = w64 & 3;
      *(unsigned*)(h0s + b * KP + slw * 8 + q2 * 2) = (unsigned)v0[k];
      *(unsigned*)(h1s + b * KP + slw * 8 + q2 * 2) = (unsigned)v1[k];
    }
    __syncthreads();   // sync1: staged LDS visible

    // ---- D: fused MFMA (L0: 16, L1: 32) + in-register epilogues ----
    f4v a0A = {0.f,0.f,0.f,0.f}, a0B = {0.f,0.f,0.f,0.f};
    f4v a1A = {0.f,0.f,0.f,0.f}, a1B = {0.f,0.f,0.f,0.f};
    const short* H0f = h0s + l15 * KP + q * 8;
    const short* H1f = h1s + l15 * KP + q * 8;
    #pragma unroll
    for (int kt = 0; kt < 8; ++kt) {
      s8v h0v = *(const s8v*)(H0f + kt * 32);
      s8v h1v = *(const s8v*)(H1f + kt * 32);
      a0A = __builtin_amdgcn_mfma_f32_16x16x32_bf16(Wf[0][0][kt], h0v, a0A, 0, 0, 0);
      a0B = __builtin_amdgcn_mfma_f32_16x16x32_bf16(Wf[0][1][kt], h0v, a0B, 0, 0, 0);
      a1A = __builtin_amdgcn_mfma_f32_16x16x32_bf16(Wf[1][0][kt], h0v, a1A, 0, 0, 0);
      a1B = __builtin_amdgcn_mfma_f32_16x16x32_bf16(Wf[1][1][kt], h0v, a1B, 0, 0, 0);
      a1A = __builtin_amdgcn_mfma_f32_16x16x32_bf16(Wf[2][0][kt], h1v, a1A, 0, 0, 0);
      a1B = __builtin_amdgcn_mfma_f32_16x16x32_bf16(Wf[2][1][kt], h1v, a1B, 0, 0, 0);
    }

    unsigned pk0 = 0, pk1 = 0;
    if (s < Tz) {
      float xv = xls[l15 * XS + s];
      float iA = sigm  (a0A[0] + xv * wihA[0] + b0A[0]);
      float fA = sigm  (a0A[1] + xv * wihA[1] + b0A[1]);
      float gA = tanh_f(a0A[2] + xv * wihA[2] + b0A[2]);
      float oA = sigm  (a0A[3] + xv * wihA[3] + b0A[3]);
      c0A = fA * c0A + iA * gA;
      float iB = sigm  (a0B[0] + xv * wihB[0] + b0B[0]);
      float fB = sigm  (a0B[1] + xv * wihB[1] + b0B[1]);
      float gB = tanh_f(a0B[2] + xv * wihB[2] + b0B[2]);
      float oB = sigm  (a0B[3] + xv * wihB[3] + b0B[3]);
      c0B = fB * c0B + iB * gB;
      pk0 = (unsigned)(unsigned short)f2bf(oA * tanh_f(c0A))
          | ((unsigned)(unsigned short)f2bf(oB * tanh_f(c0B)) << 16);
    }
    if (s >= 1) {
      float iA = sigm  (a1A[0] + b1A[0]);
      float fA = sigm  (a1A[1] + b1A[1]);
      float gA = tanh_f(a1A[2] + b1A[2]);
      float oA = sigm  (a1A[3] + b1A[3]);
      c1A = fA * c1A + iA * gA;
      float iB = sigm  (a1B[0] + b1B[0]);
      float fB = sigm  (a1B[1] + b1B[1]);
      float gB = tanh_f(a1B[2] + b1B[2]);
      float oB = sigm  (a1B[3] + b1B[3]);
      c1B = fB * c1B + iB * gB;
      pk1 = (unsigned)(unsigned short)f2bf(oA * tanh_f(c1A))
          | ((unsigned)(unsigned short)f2bf(oB * tanh_f(c1B)) << 16);
    }
    __syncthreads();   // sync2: all MFMA LDS reads done; next B may overwrite

    // ---- E: stamped coalesced stores (ack drains under next poll) ----
    {
      const u64 stamp = (u64)(unsigned)(s + 2) << 32;
      size_t base = (size_t)(sl * 4 + w) * 2048 + (size_t)(gbase + l15) * 4 + q;
      if (s < Tz)
        llc_store(h0g + (size_t)(s & 1) * HWORDS + base, stamp | pk0);
      if (s >= 1)
        llc_store(h1g + (size_t)((s - 1) & 1) * HWORDS + base, stamp | pk1);
    }
  }

  // ---- final head (sl==0 blocks): out = h1[T-1] @ w_lin^T + b_lin ----
  if (sl == 0) {
    const u64* p1 = h1g + (size_t)((Tz - 1) & 1) * HWORDS;
    const unsigned expd = (unsigned)(Tz + 2);
    u64 v[8];
    #pragma unroll
    for (int k = 0; k < 8; ++k) {
      int i = k * 256 + tid;
      size_t gi = (size_t)(i >> 6) * 2048 + (size_t)gbase * 4 + (i & 63);
      v[k] = llc_load(p1 + gi);
    }
    while (true) {
      bool ok = true;
      #pragma unroll
      for (int k = 0; k < 8; ++k) ok = ok && ((unsigned)(v[k] >> 32) == expd);
      if (ok) break;
      __builtin_amdgcn_s_sleep(1);
      #pragma unroll
      for (int k = 0; k < 8; ++k) {
        int i = k * 256 + tid;
        size_t gi = (size_t)(i >> 6) * 2048 + (size_t)gbase * 4 + (i & 63);
        if ((unsigned)(v[k] >> 32) != expd) v[k] = llc_load(p1 + gi);
      }
    }
    #pragma unroll
    for (int k = 0; k < 8; ++k) {
      int i = k * 256 + tid;
      int slw = i >> 6, w64 = i & 63;
      int b = w64 >> 2, q2 = w64 & 3;
      *(unsigned*)(h0s + b * KP + slw * 8 + q2 * 2) = (unsigned)v[k];
    }
    __syncthreads();
    for (int i = tid; i < BT * Pz; i += 256) {
      int b = i / Pz, p = i - b * Pz;
      const float* wr = wls + p * Hz;
      float acc = b_lin[p];
      for (int kk = 0; kk < Hz; ++kk)
        acc += bf2f(h0s[b * KP + kk]) * wr[kk];   // both in kpos order
      out[(gbase + b) * Pz + p] = acc;
    }
  }
}

extern "C" void kernel_launch(void* const* d_in, const int* in_sizes, int n_in,
                              void* d_out, int out_size, void* d_ws, size_t ws_size,
                              hipStream_t stream) {
  const float* x     = (const float*)d_in[0];
  const float* w_ih0 = (const float*)d_in[1];
  const float* w_hh0 = (const float*)d_in[2];
  const float* b_ih0 = (const float*)d_in[3];
  const float* b_hh0 = (const float*)d_in[4];
  const float* w_ih1 = (const float*)d_in[5];
  const float* w_hh1 = (const float*)d_in[6];
  const float* b_ih1 = (const float*)d_in[7];
  const float* b_hh1 = (const float*)d_in[8];
  const float* w_lin = (const float*)d_in[9];
  const float* b_lin = (const float*)d_in[10];
  float* out = (float*)d_out;

  unsigned char* ws = (unsigned char*)d_ws;
  u64* h0g = (u64*)ws;                            // [2][HWORDS] stamped u64
  u64* h1g = (u64*)(ws + 2 * HWORDS * 8);         // [2][HWORDS]

  hinit<<<256, 256, 0, stream>>>(h0g, h1g);

  size_t lds_bytes = (size_t)(2 * BT) * KP * 2    // h staging
                   + (size_t)(BT * XS) * 4        // x preload
                   + (size_t)(Pz * Hz) * 4;       // permuted w_lin (head)
  hipFuncSetAttribute((const void*)lstm2,
                      hipFuncAttributeMaxDynamicSharedMemorySize, (int)lds_bytes);
  lstm2<<<GB * GS, 256, lds_bytes, stream>>>(x, w_ih0, w_hh0, b_ih0, b_hh0,
                                             w_ih1, w_hh1, b_ih1, b_hh1,
                                             w_lin, b_lin, out, h0g, h1g);
}

// Round 9
// 800.375 us; speedup vs baseline: 1.2878x; 1.2878x over previous
//
#include <hip/hip_runtime.h>

// Problem constants
constexpr int Bz = 512;   // batch
constexpr int Tz = 256;   // seq len
constexpr int Hz = 256;   // hidden
constexpr int Pz = 14;    // predict dim
constexpr int GB = 32;    // batch groups
constexpr int GS = 8;     // hidden slices per group
constexpr int BT = 16;    // batch per group (512/32)
constexpr int KP = 264;   // LDS h row stride (shorts)
constexpr int XS = 260;   // x LDS row stride (floats)

typedef short s8v __attribute__((ext_vector_type(8)));
typedef float f4v __attribute__((ext_vector_type(4)));
typedef unsigned long long u64;

__device__ __forceinline__ short f2bf(float f) {
  unsigned u = __float_as_uint(f);
  u = (u + 0x7fffu + ((u >> 16) & 1u)) >> 16;   // RNE
  return (short)u;
}
__device__ __forceinline__ float bf2f(short s) {
  return __uint_as_float(((unsigned)(unsigned short)s) << 16);
}
__device__ __forceinline__ float sigm(float v) { return 1.0f / (1.0f + __expf(-v)); }
__device__ __forceinline__ float tanh_f(float v) { return 1.0f - 2.0f / (__expf(2.0f * v) + 1.0f); }

__device__ __forceinline__ u64 llc_load64(const u64* p) {
  return __hip_atomic_load(p, __ATOMIC_RELAXED, __HIP_MEMORY_SCOPE_AGENT);
}
__device__ __forceinline__ unsigned llc_load32(const unsigned* p) {
  return __hip_atomic_load(p, __ATOMIC_RELAXED, __HIP_MEMORY_SCOPE_AGENT);
}
__device__ __forceinline__ void llc_store32(unsigned* p, unsigned v) {
  __hip_atomic_store(p, v, __ATOMIC_RELAXED, __HIP_MEMORY_SCOPE_AGENT);
}

// R9 = R5 (918us, proven) with the central counter barrier replaced by
// per-producer completion flags:
//   - producer: data stores (sc1) -> __syncthreads (drains vmcnt(0) per wave,
//     R5-proven => stores visible at LLC) -> tid0 stores flags[g][sl] = s+1
//     (fire-and-forget, no RMW serialization, no tid0 poll, no trailing sync).
//   - consumer: ALL waves poll the group's 8 contiguous flags (one line) via
//     relaxed sc1 loads + __ballot; proceed when all >= s.
// flag = #completed steps, so memset(0) initializes everything (no init
// kernel; bf16 zeros == 0x0000 covers the t<0 hidden state).
// Safety: poll(>=s) passing => every peer finished step s-1 => their stage
// reads of parity-(s-2) data returned => my parity-s overwrite is safe.
__global__ void __launch_bounds__(256, 1)
lstm2(const float* __restrict__ x,
      const float* __restrict__ w_ih0, const float* __restrict__ w_hh0,
      const float* __restrict__ b_ih0, const float* __restrict__ b_hh0,
      const float* __restrict__ w_ih1, const float* __restrict__ w_hh1,
      const float* __restrict__ b_ih1, const float* __restrict__ b_hh1,
      const float* __restrict__ w_lin, const float* __restrict__ b_lin,
      float* __restrict__ out,
      unsigned* __restrict__ h0g, unsigned* __restrict__ h1g,
      unsigned* __restrict__ flags)
{
  const int blk  = blockIdx.x;
  const int g    = blk >> 3;      // batch group (32)
  const int sl   = blk & 7;       // hidden slice (8)
  const int tid  = threadIdx.x;
  const int w    = tid >> 6;      // wave
  const int lane = tid & 63;
  const int q    = lane >> 4;
  const int l15  = lane & 15;     // batch within group
  const int gbase = g * BT;

  extern __shared__ char smem_raw[];
  short* h0s = (short*)smem_raw;          // [BT][KP] staged h0[s-1], kpos order
  short* h1s = h0s + BT * KP;             // [BT][KP] staged h1[s-2]
  float* xls = (float*)(h1s + BT * KP);   // [BT][XS] x preload
  float* wls = xls + BT * XS;             // [Pz][256] w_lin permuted to kpos order

  // ---- one-time: weights -> register A-fragments (permuted k gather) ----
  // kpos = sl*32 + w*8 + q*2 + j  <->  k_true = sl*32 + w*4 + q + 16*j
  s8v Wf[3][2][8];   // [mat: hh0, ih1, hh1][mti][kt]
  {
    const float* wsrc[3] = {w_hh0, w_ih1, w_hh1};
    #pragma unroll
    for (int mat = 0; mat < 3; ++mat) {
      #pragma unroll
      for (int mti = 0; mti < 2; ++mti) {
        int rr = (w + mti * 4) * 16 + l15;          // rr = unit*4+gate
        int grow = (rr & 3) * Hz + sl * 32 + (rr >> 2);
        const float* p = wsrc[mat] + (size_t)grow * Hz;
        #pragma unroll
        for (int kt = 0; kt < 8; ++kt) {
          s8v f;
          #pragma unroll
          for (int j = 0; j < 8; ++j) {
            int ktrue = kt * 32 + q * 4 + (j >> 1) + 16 * (j & 1);
            f[j] = f2bf(p[ktrue]);
          }
          Wf[mat][mti][kt] = f;
        }
      }
    }
  }
  // per-lane epilogue constants: units uA = w*4+q, uB = 16+uA; gates r=0..3
  const int uA = w * 4 + q, uB = 16 + w * 4 + q;
  float wihA[4], wihB[4], b0A[4], b0B[4], b1A[4], b1B[4];
  #pragma unroll
  for (int r = 0; r < 4; ++r) {
    int ga_ = r * Hz + sl * 32 + uA;
    int gb_ = r * Hz + sl * 32 + uB;
    wihA[r] = w_ih0[ga_];              wihB[r] = w_ih0[gb_];
    b0A[r]  = b_ih0[ga_] + b_hh0[ga_]; b0B[r]  = b_ih0[gb_] + b_hh0[gb_];
    b1A[r]  = b_ih1[ga_] + b_hh1[ga_]; b1B[r]  = b_ih1[gb_] + b_hh1[gb_];
  }
  float c0A = 0.f, c0B = 0.f, c1A = 0.f, c1B = 0.f;   // cell states in VGPRs

  // ---- preload x (this group's 16 batches) and permuted w_lin (head) ----
  for (int i = tid; i < BT * (Tz / 4); i += 256) {
    int b = i >> 6, c4 = i & 63;
    f4v v = *(const f4v*)(x + (size_t)(gbase + b) * Tz + c4 * 4);
    *(f4v*)(xls + b * XS + c4 * 4) = v;
  }
  if (sl == 0) {
    for (int i = tid; i < Pz * Hz; i += 256) {
      int p = i >> 8, kpos = i & 255;
      int sl2 = kpos >> 5, w2 = (kpos >> 3) & 3, q2 = (kpos >> 1) & 3, jj = kpos & 1;
      wls[i] = w_lin[p * Hz + sl2 * 32 + w2 * 4 + q2 + 16 * jj];
    }
  }

  const unsigned* myflags = flags + g * 32 + (lane & 7);  // group's 8 flags, one line
  unsigned* myflag = flags + g * 32 + sl;

  for (int s = 0; s <= Tz; ++s) {
    // ---- A: all-wave flag poll: all 8 producers completed step s-1 ----
    {
      const unsigned expd = (unsigned)s;
      unsigned f = llc_load32(myflags);
      while (__ballot(f >= expd) != ~0ull) {
        __builtin_amdgcn_s_sleep(1);
        f = llc_load32(myflags);
      }
    }

    // ---- B: stage h0[s-1] (parity (s+1)&1) and h1[s-2] (parity s&1) ----
    {
      const u64* s0 = (const u64*)h0g + (size_t)((s + 1) & 1) * 32768;
      const u64* s1 = (const u64*)h1g + (size_t)(s & 1) * 32768;
      u64 r0[4], r1[4];
      #pragma unroll
      for (int k = 0; k < 4; ++k) {
        int i = tid + k * 256;
        int c = i & 1, b = (i >> 1) & 15, slw = i >> 5;
        size_t gi = ((size_t)slw * Bz + gbase + b) * 2 + c;
        r0[k] = llc_load64(s0 + gi);
        r1[k] = llc_load64(s1 + gi);
      }
      #pragma unroll
      for (int k = 0; k < 4; ++k) {
        int i = tid + k * 256;
        int c = i & 1, b = (i >> 1) & 15, slw = i >> 5;
        *(u64*)(h0s + b * KP + slw * 8 + c * 4) = r0[k];
        *(u64*)(h1s + b * KP + slw * 8 + c * 4) = r1[k];
      }
    }
    __syncthreads();   // sync1: staged LDS visible

    // ---- C: fused MFMA (L0: 16, L1: 32); weights from regs; 16 b128 reads ----
    f4v a0A = {0.f,0.f,0.f,0.f}, a0B = {0.f,0.f,0.f,0.f};
    f4v a1A = {0.f,0.f,0.f,0.f}, a1B = {0.f,0.f,0.f,0.f};
    const short* H0f = h0s + l15 * KP + q * 8;
    const short* H1f = h1s + l15 * KP + q * 8;
    #pragma unroll
    for (int kt = 0; kt < 8; ++kt) {
      s8v h0v = *(const s8v*)(H0f + kt * 32);
      s8v h1v = *(const s8v*)(H1f + kt * 32);
      a0A = __builtin_amdgcn_mfma_f32_16x16x32_bf16(Wf[0][0][kt], h0v, a0A, 0, 0, 0);
      a0B = __builtin_amdgcn_mfma_f32_16x16x32_bf16(Wf[0][1][kt], h0v, a0B, 0, 0, 0);
      a1A = __builtin_amdgcn_mfma_f32_16x16x32_bf16(Wf[1][0][kt], h0v, a1A, 0, 0, 0);
      a1B = __builtin_amdgcn_mfma_f32_16x16x32_bf16(Wf[1][1][kt], h0v, a1B, 0, 0, 0);
      a1A = __builtin_amdgcn_mfma_f32_16x16x32_bf16(Wf[2][0][kt], h1v, a1A, 0, 0, 0);
      a1B = __builtin_amdgcn_mfma_f32_16x16x32_bf16(Wf[2][1][kt], h1v, a1B, 0, 0, 0);
    }

    // ---- D: in-register epilogues -> one packed u32 per lane per layer ----
    unsigned pk0 = 0, pk1 = 0;
    if (s < Tz) {
      float xv = xls[l15 * XS + s];
      float iA = sigm  (a0A[0] + xv * wihA[0] + b0A[0]);
      float fA = sigm  (a0A[1] + xv * wihA[1] + b0A[1]);
      float gA = tanh_f(a0A[2] + xv * wihA[2] + b0A[2]);
      float oA = sigm  (a0A[3] + xv * wihA[3] + b0A[3]);
      c0A = fA * c0A + iA * gA;
      float iB = sigm  (a0B[0] + xv * wihB[0] + b0B[0]);
      float fB = sigm  (a0B[1] + xv * wihB[1] + b0B[1]);
      float gB = tanh_f(a0B[2] + xv * wihB[2] + b0B[2]);
      float oB = sigm  (a0B[3] + xv * wihB[3] + b0B[3]);
      c0B = fB * c0B + iB * gB;
      pk0 = (unsigned)(unsigned short)f2bf(oA * tanh_f(c0A))
          | ((unsigned)(unsigned short)f2bf(oB * tanh_f(c0B)) << 16);
    }
    if (s >= 1) {
      float iA = sigm  (a1A[0] + b1A[0]);
      float fA = sigm  (a1A[1] + b1A[1]);
      float gA = tanh_f(a1A[2] + b1A[2]);
      float oA = sigm  (a1A[3] + b1A[3]);
      c1A = fA * c1A + iA * gA;
      float iB = sigm  (a1B[0] + b1B[0]);
      float fB = sigm  (a1B[1] + b1B[1]);
      float gB = tanh_f(a1B[2] + b1B[2]);
      float oB = sigm  (a1B[3] + b1B[3]);
      c1B = fB * c1B + iB * gB;
      pk1 = (unsigned)(unsigned short)f2bf(oA * tanh_f(c1A))
          | ((unsigned)(unsigned short)f2bf(oB * tanh_f(c1B)) << 16);
    }

    // ---- E: coalesced permuted data stores (sc1) ----
    {
      size_t base = (size_t)(sl * 4 + w) * 2048 + (size_t)(gbase + l15) * 4 + q;
      if (s < Tz)
        llc_store32(h0g + (size_t)(s & 1) * 65536 + base, pk0);
      if (s >= 1)
        llc_store32(h1g + (size_t)((s - 1) & 1) * 65536 + base, pk1);
    }

    // ---- F: drain + flag. __syncthreads emits per-wave s_waitcnt vmcnt(0)
    // before s_barrier (R5-proven), so after the barrier ALL waves' data
    // stores are at the LLC; tid0's flag store then publishes completion. ----
    __syncthreads();
    if (tid == 0)
      llc_store32(myflag, (unsigned)(s + 1));
  }

  // ---- final head (sl==0 blocks): out = h1[T-1] @ w_lin^T + b_lin ----
  if (sl == 0) {
    {
      const unsigned expd = (unsigned)(Tz + 1);
      unsigned f = llc_load32(myflags);
      while (__ballot(f >= expd) != ~0ull) {
        __builtin_amdgcn_s_sleep(1);
        f = llc_load32(myflags);
      }
    }
    const u64* s1 = (const u64*)h1g + (size_t)((Tz - 1) & 1) * 32768;
    for (int k = 0; k < 4; ++k) {
      int i = tid + k * 256;
      int c = i & 1, b = (i >> 1) & 15, slw = i >> 5;
      u64 v = llc_load64(s1 + ((size_t)slw * Bz + gbase + b) * 2 + c);
      *(u64*)(h0s + b * KP + slw * 8 + c * 4) = v;
    }
    __syncthreads();
    for (int i = tid; i < BT * Pz; i += 256) {
      int b = i / Pz, p = i - b * Pz;
      const float* wr = wls + p * Hz;
      float acc = b_lin[p];
      for (int kk = 0; kk < Hz; ++kk)
        acc += bf2f(h0s[b * KP + kk]) * wr[kk];   // both in kpos order
      out[(gbase + b) * Pz + p] = acc;
    }
  }
}

extern "C" void kernel_launch(void* const* d_in, const int* in_sizes, int n_in,
                              void* d_out, int out_size, void* d_ws, size_t ws_size,
                              hipStream_t stream) {
  const float* x     = (const float*)d_in[0];
  const float* w_ih0 = (const float*)d_in[1];
  const float* w_hh0 = (const float*)d_in[2];
  const float* b_ih0 = (const float*)d_in[3];
  const float* b_hh0 = (const float*)d_in[4];
  const float* w_ih1 = (const float*)d_in[5];
  const float* w_hh1 = (const float*)d_in[6];
  const float* b_ih1 = (const float*)d_in[7];
  const float* b_hh1 = (const float*)d_in[8];
  const float* w_lin = (const float*)d_in[9];
  const float* b_lin = (const float*)d_in[10];
  float* out = (float*)d_out;

  unsigned char* ws = (unsigned char*)d_ws;
  unsigned* h0g   = (unsigned*)ws;                     // [2][65536] u32 (256 KB/parity)
  unsigned* h1g   = (unsigned*)(ws + (512 << 10));     // [2][65536] u32
  unsigned* flags = (unsigned*)(ws + (1024 << 10));    // [32 groups][32] u32 (8 used/group)
  // memset(0): h data zeros (bf16 0x0000 = initial hidden state) + flags = 0
  // ("0 steps completed") -- no init kernel needed.
  hipMemsetAsync(d_ws, 0, (1024 << 10) + 4096, stream);

  size_t lds_bytes = (size_t)(2 * BT) * KP * 2     // h staging
                   + (size_t)(BT * XS) * 4         // x preload
                   + (size_t)(Pz * Hz) * 4;        // permuted w_lin (head)
  hipFuncSetAttribute((const void*)lstm2,
                      hipFuncAttributeMaxDynamicSharedMemorySize, (int)lds_bytes);
  lstm2<<<GB * GS, 256, lds_bytes, stream>>>(x, w_ih0, w_hh0, b_ih0, b_hh0,
                                             w_ih1, w_hh1, b_ih1, b_hh1,
                                             w_lin, b_lin, out, h0g, h1g, flags);
}